// Round 1
// baseline (84.745 us; speedup 1.0000x reference)
//
#include <hip/hip_runtime.h>

// Problem constants (fixed by setup_inputs)
constexpr int B  = 32;
constexpr int M  = 512;    // entities per batch
constexpr int N  = 128;    // channels
constexpr int H  = 128;
constexpr int W  = 128;
constexpr int HW = H * W;            // 16384 = 2^14
constexpr int PLANE = N * HW;        // 2^21 elements per batch in output

// ---------------------------------------------------------------------------
// Kernel 1: fill inv[] with -1 (int4-vectorized).
// inv has B*HW = 524288 ints = 2 MB in workspace.
// ---------------------------------------------------------------------------
__global__ void init_inv_kernel(int* __restrict__ inv) {
    int t = blockIdx.x * blockDim.x + threadIdx.x;   // B*HW/4 = 131072 threads
    int4 v = make_int4(-1, -1, -1, -1);
    reinterpret_cast<int4*>(inv)[t] = v;
}

// ---------------------------------------------------------------------------
// Kernel 2: scatter entity indices into the inverse map.
// One thread per (b, m): inv[b*HW + y*W + x] = m.  Locations are guaranteed
// non-overlapping per batch, so no atomics needed.
// ---------------------------------------------------------------------------
__global__ void build_inv_kernel(const int* __restrict__ loc, int* __restrict__ inv) {
    int tid = blockIdx.x * blockDim.x + threadIdx.x;  // B*M = 16384 threads
    int b = tid >> 9;            // / M (M=512)
    int y = loc[tid * 2 + 0];
    int x = loc[tid * 2 + 1];
    inv[b * HW + y * W + x] = tid & (M - 1);          // m
}

// ---------------------------------------------------------------------------
// Kernel 3: write the whole output as a gather (fuses zero-fill + scatter).
// out[b, n, p] = inv[b,p] >= 0 ? x[b, inv[b,p], n] : 0
// Each thread produces one float4 of consecutive p for fixed (b, n):
// fully coalesced 16B stores; int4 inv loads (cache-resident after first n).
// ---------------------------------------------------------------------------
__global__ void gather_out_kernel(const float* __restrict__ x,
                                  const int* __restrict__ inv,
                                  float* __restrict__ out) {
    int t = blockIdx.x * blockDim.x + threadIdx.x;    // B*PLANE/4 = 16,777,216
    int e = t << 2;                                    // output element index
    int b   = e >> 21;                                 // / PLANE
    int rem = e & (PLANE - 1);
    int n   = rem >> 14;                               // / HW
    int p   = rem & (HW - 1);

    const int4 iv = *reinterpret_cast<const int4*>(inv + b * HW + p);
    const float* xb = x + b * (M * N) + n;             // x[b, :, n], stride N

    float4 o;
    o.x = (iv.x >= 0) ? xb[iv.x * N] : 0.0f;
    o.y = (iv.y >= 0) ? xb[iv.y * N] : 0.0f;
    o.z = (iv.z >= 0) ? xb[iv.z * N] : 0.0f;
    o.w = (iv.w >= 0) ? xb[iv.w * N] : 0.0f;

    *reinterpret_cast<float4*>(out + e) = o;
}

// ---------------------------------------------------------------------------
extern "C" void kernel_launch(void* const* d_in, const int* in_sizes, int n_in,
                              void* d_out, int out_size, void* d_ws, size_t ws_size,
                              hipStream_t stream) {
    const float* x   = (const float*)d_in[0];
    const int*   loc = (const int*)d_in[1];
    // d_in[2] = H, d_in[3] = W (scalars; fixed at 128, hard-coded above)
    float* out = (float*)d_out;
    int*   inv = (int*)d_ws;      // needs B*HW*4 = 2 MB of workspace

    // 1) inv = -1 everywhere
    init_inv_kernel<<<(B * HW / 4) / 256, 256, 0, stream>>>(inv);
    // 2) inv[b, y*W+x] = m
    build_inv_kernel<<<(B * M) / 256, 256, 0, stream>>>(loc, inv);
    // 3) full coalesced output write
    gather_out_kernel<<<(B * PLANE / 4) / 256, 256, 0, stream>>>(x, inv, out);
}

// Round 2
// 59.394 us; speedup vs baseline: 1.4268x; 1.4268x over previous
//
#include <hip/hip_runtime.h>

// Problem constants (fixed by setup_inputs)
constexpr int B  = 32;
constexpr int M  = 512;    // entities per batch
constexpr int N  = 128;    // channels
constexpr int H  = 128;
constexpr int W  = 128;
constexpr int HW = H * W;            // 16384 = 2^14
constexpr int PLANE = N * HW;        // 2^21 elements per batch in output

typedef float f4 __attribute__((ext_vector_type(4)));
typedef int   i4 __attribute__((ext_vector_type(4)));

// ---------------------------------------------------------------------------
// Kernel 1: fill inv[] with -1 (int4-vectorized). 2 MB in workspace.
// ---------------------------------------------------------------------------
__global__ void init_inv_kernel(int* __restrict__ inv) {
    int t = blockIdx.x * blockDim.x + threadIdx.x;   // B*HW/4 = 131072 threads
    i4 v = {-1, -1, -1, -1};
    reinterpret_cast<i4*>(inv)[t] = v;
}

// ---------------------------------------------------------------------------
// Kernel 2: scatter entity indices into the inverse map (no overlap -> no atomics).
// ---------------------------------------------------------------------------
__global__ void build_inv_kernel(const int* __restrict__ loc, int* __restrict__ inv) {
    int tid = blockIdx.x * blockDim.x + threadIdx.x;  // B*M = 16384 threads
    int b = tid >> 9;            // / M (M=512)
    int y = loc[tid * 2 + 0];
    int x = loc[tid * 2 + 1];
    inv[b * HW + y * W + x] = tid & (M - 1);          // m
}

// ---------------------------------------------------------------------------
// Kernel 3: full output written as a gather, tiled 4p x 8n per thread.
//   - inv loaded once (int4) per thread, reused for 8 n-values
//   - x gathered as float4 (x[b,m,nh..nh+3] contiguous)
//   - stores are nontemporal float4 -> pure write stream, L2 kept for reads
// Thread mapping: t = [b:5][nb:4][p4:12]; consecutive threads = consecutive p
// so every store is a coalesced 1 KB/wave stream.
// ---------------------------------------------------------------------------
__global__ void gather_out_kernel(const float* __restrict__ x,
                                  const int* __restrict__ inv,
                                  float* __restrict__ out) {
    int t  = blockIdx.x * blockDim.x + threadIdx.x;   // 2,097,152 threads
    int p  = (t & 4095) << 2;        // p, p+1, p+2, p+3
    int nb = (t >> 12) & 15;         // n-block of 8
    int b  = t >> 16;
    int n0 = nb << 3;

    const i4 iv = *reinterpret_cast<const i4*>(inv + (b << 14) + p);
    const float* xb = x + (b << 16);                  // x[b], row stride N=128
    float* ob = out + (b << 21) + (n0 << 14) + p;

    const f4 zero = {0.f, 0.f, 0.f, 0.f};

    #pragma unroll
    for (int h = 0; h < 2; ++h) {
        const int nh = n0 + (h << 2);
        f4 x0 = (iv[0] >= 0) ? *reinterpret_cast<const f4*>(xb + (iv[0] << 7) + nh) : zero;
        f4 x1 = (iv[1] >= 0) ? *reinterpret_cast<const f4*>(xb + (iv[1] << 7) + nh) : zero;
        f4 x2 = (iv[2] >= 0) ? *reinterpret_cast<const f4*>(xb + (iv[2] << 7) + nh) : zero;
        f4 x3 = (iv[3] >= 0) ? *reinterpret_cast<const f4*>(xb + (iv[3] << 7) + nh) : zero;

        float* o = ob + (h << 16);    // + h*4*HW
        #pragma unroll
        for (int j = 0; j < 4; ++j) { // n = nh + j
            f4 v = {x0[j], x1[j], x2[j], x3[j]};
            __builtin_nontemporal_store(v, reinterpret_cast<f4*>(o + (j << 14)));
        }
    }
}

// ---------------------------------------------------------------------------
extern "C" void kernel_launch(void* const* d_in, const int* in_sizes, int n_in,
                              void* d_out, int out_size, void* d_ws, size_t ws_size,
                              hipStream_t stream) {
    const float* x   = (const float*)d_in[0];
    const int*   loc = (const int*)d_in[1];
    // d_in[2] = H, d_in[3] = W (scalars; fixed at 128, hard-coded above)
    float* out = (float*)d_out;
    int*   inv = (int*)d_ws;      // needs B*HW*4 = 2 MB of workspace

    init_inv_kernel<<<(B * HW / 4) / 256, 256, 0, stream>>>(inv);
    build_inv_kernel<<<(B * M) / 256, 256, 0, stream>>>(loc, inv);
    gather_out_kernel<<<(B * PLANE / 32) / 256, 256, 0, stream>>>(x, inv, out);
}

// Round 3
// 55.759 us; speedup vs baseline: 1.5199x; 1.0652x over previous
//
#include <hip/hip_runtime.h>

// Problem constants (fixed by setup_inputs)
constexpr int B  = 32;
constexpr int M  = 512;    // entities per batch
constexpr int N  = 128;    // channels
constexpr int H  = 128;
constexpr int W  = 128;
constexpr int HW = H * W;            // 16384 = 2^14
constexpr int PLANE = N * HW;        // 2^21 elements per batch in output
constexpr size_t INV_BYTES = (size_t)B * HW * 4;   // 2 MB

typedef float f4 __attribute__((ext_vector_type(4)));
typedef int   i4 __attribute__((ext_vector_type(4)));

// ---------------------------------------------------------------------------
// Kernel 1: fill inv[] with -1 (int4-vectorized) and zero the 64 B zero page.
// ---------------------------------------------------------------------------
__global__ void init_inv_kernel(int* __restrict__ inv, float* __restrict__ zpage) {
    int t = blockIdx.x * blockDim.x + threadIdx.x;   // 131072 threads
    i4 v = {-1, -1, -1, -1};
    reinterpret_cast<i4*>(inv)[t] = v;
    if (zpage && t < 4) {
        f4 z = {0.f, 0.f, 0.f, 0.f};
        reinterpret_cast<f4*>(zpage)[t] = z;
    }
}

// ---------------------------------------------------------------------------
// Kernel 2: scatter entity indices into the inverse map (no overlap -> no atomics).
// ---------------------------------------------------------------------------
__global__ void build_inv_kernel(const int* __restrict__ loc, int* __restrict__ inv) {
    int tid = blockIdx.x * blockDim.x + threadIdx.x;  // B*M = 16384 threads
    int b = tid >> 9;            // / M (M=512)
    int y = loc[tid * 2 + 0];
    int x = loc[tid * 2 + 1];
    inv[b * HW + y * W + x] = tid & (M - 1);          // m
}

// ---------------------------------------------------------------------------
// Kernel 3 (primary): full output as a gather, tiled 4p x 8n per thread.
//   - branch-free: invalid lanes read a 64 B zero page (L1 broadcast)
//   - all 8 x-loads hoisted before all 8 stores (latency overlap)
//   - plain cached stores (fill kernel proves 7 TB/s through L2)
// ---------------------------------------------------------------------------
__global__ void gather_zp_kernel(const float* __restrict__ x,
                                 const int* __restrict__ inv,
                                 const float* __restrict__ zpage,
                                 float* __restrict__ out) {
    int t  = blockIdx.x * blockDim.x + threadIdx.x;   // 2,097,152 threads
    int p  = (t & 4095) << 2;        // p .. p+3
    int nb = (t >> 12) & 15;         // n-block of 8
    int b  = t >> 16;
    int n0 = nb << 3;

    const i4 iv = *reinterpret_cast<const i4*>(inv + (b << 14) + p);
    const float* xb = x + (b << 16);                  // x[b], row stride N=128
    float* ob = out + (b << 21) + (n0 << 14) + p;

    // Per-p source addresses; invalid -> zero page (uniform flow, no branches)
    const float* a0 = (iv[0] >= 0) ? (xb + (iv[0] << 7) + n0) : zpage;
    const float* a1 = (iv[1] >= 0) ? (xb + (iv[1] << 7) + n0) : zpage;
    const float* a2 = (iv[2] >= 0) ? (xb + (iv[2] << 7) + n0) : zpage;
    const float* a3 = (iv[3] >= 0) ? (xb + (iv[3] << 7) + n0) : zpage;

    f4 xv[2][4];
    #pragma unroll
    for (int h = 0; h < 2; ++h) {
        xv[h][0] = *reinterpret_cast<const f4*>(a0 + (h << 2));
        xv[h][1] = *reinterpret_cast<const f4*>(a1 + (h << 2));
        xv[h][2] = *reinterpret_cast<const f4*>(a2 + (h << 2));
        xv[h][3] = *reinterpret_cast<const f4*>(a3 + (h << 2));
    }

    #pragma unroll
    for (int h = 0; h < 2; ++h) {
        float* o = ob + (h << 16);    // + h*4*HW
        #pragma unroll
        for (int j = 0; j < 4; ++j) { // n = n0 + h*4 + j
            f4 v = {xv[h][0][j], xv[h][1][j], xv[h][2][j], xv[h][3][j]};
            *reinterpret_cast<f4*>(o + (j << 14)) = v;
        }
    }
}

// ---------------------------------------------------------------------------
// Kernel 3 (fallback if ws has no room for the zero page): select-based.
// ---------------------------------------------------------------------------
__global__ void gather_sel_kernel(const float* __restrict__ x,
                                  const int* __restrict__ inv,
                                  float* __restrict__ out) {
    int t  = blockIdx.x * blockDim.x + threadIdx.x;
    int p  = (t & 4095) << 2;
    int nb = (t >> 12) & 15;
    int b  = t >> 16;
    int n0 = nb << 3;

    const i4 iv = *reinterpret_cast<const i4*>(inv + (b << 14) + p);
    const float* xb = x + (b << 16);
    float* ob = out + (b << 21) + (n0 << 14) + p;
    const f4 zero = {0.f, 0.f, 0.f, 0.f};

    int m0 = iv[0] < 0 ? 0 : iv[0], m1 = iv[1] < 0 ? 0 : iv[1];
    int m2 = iv[2] < 0 ? 0 : iv[2], m3 = iv[3] < 0 ? 0 : iv[3];

    f4 xv[2][4];
    #pragma unroll
    for (int h = 0; h < 2; ++h) {
        const int nh = n0 + (h << 2);
        xv[h][0] = (iv[0] >= 0) ? *reinterpret_cast<const f4*>(xb + (m0 << 7) + nh) : zero;
        xv[h][1] = (iv[1] >= 0) ? *reinterpret_cast<const f4*>(xb + (m1 << 7) + nh) : zero;
        xv[h][2] = (iv[2] >= 0) ? *reinterpret_cast<const f4*>(xb + (m2 << 7) + nh) : zero;
        xv[h][3] = (iv[3] >= 0) ? *reinterpret_cast<const f4*>(xb + (m3 << 7) + nh) : zero;
    }

    #pragma unroll
    for (int h = 0; h < 2; ++h) {
        float* o = ob + (h << 16);
        #pragma unroll
        for (int j = 0; j < 4; ++j) {
            f4 v = {xv[h][0][j], xv[h][1][j], xv[h][2][j], xv[h][3][j]};
            *reinterpret_cast<f4*>(o + (j << 14)) = v;
        }
    }
}

// ---------------------------------------------------------------------------
extern "C" void kernel_launch(void* const* d_in, const int* in_sizes, int n_in,
                              void* d_out, int out_size, void* d_ws, size_t ws_size,
                              hipStream_t stream) {
    const float* x   = (const float*)d_in[0];
    const int*   loc = (const int*)d_in[1];
    float* out = (float*)d_out;
    int*   inv = (int*)d_ws;                           // 2 MB
    bool zp_ok = ws_size >= INV_BYTES + 64;
    float* zpage = zp_ok ? (float*)((char*)d_ws + INV_BYTES) : nullptr;

    init_inv_kernel<<<(B * HW / 4) / 256, 256, 0, stream>>>(inv, zpage);
    build_inv_kernel<<<(B * M) / 256, 256, 0, stream>>>(loc, inv);
    if (zp_ok)
        gather_zp_kernel<<<(B * PLANE / 32) / 256, 256, 0, stream>>>(x, inv, zpage, out);
    else
        gather_sel_kernel<<<(B * PLANE / 32) / 256, 256, 0, stream>>>(x, inv, out);
}